// Round 8
// baseline (671.942 us; speedup 1.0000x reference)
//
#include <hip/hip_runtime.h>

// INT4PackedLinear: y[64,28672] = x[64,8192] @ dequant(w_packed, scales) + bias
// Dtype contract (verified R0-R7): x/scales/bias/y are FLOAT32, w_packed int32.
//
// R7 post-mortem: double-buffer waited on DMAs issued only 1 phase (~350cyc) ago
// vs ~900cyc HBM latency -> per-phase stall, components serialize (~170us = sum
// of LDS 41 + VALU 18 + HBM 50-75). R8: triple-buffer circular pipeline,
// wait-BEFORE-issue (wait targets DMAs 2 phases old), ONE barrier per phase,
// 8 KB/wave (96 KB/CU) continuously in flight. 52 KB LDS -> 3 blocks/CU.

typedef short  short8  __attribute__((ext_vector_type(8)));
typedef float  float4v __attribute__((ext_vector_type(4)));
typedef int    int4v   __attribute__((ext_vector_type(4)));
typedef unsigned int uint4v __attribute__((ext_vector_type(4)));

constexpr int Kd = 8192;
constexpr int Nd = 28672;
constexpr int KSPLIT = 4;           // 4 k-partitions of 2048

__device__ __forceinline__ unsigned f32_to_bf16_rn(float f) {
    unsigned u = __builtin_bit_cast(unsigned, f);
    return (u + 0x7FFFu + ((u >> 16) & 1u)) >> 16;
}

// async global->LDS DMA: 16B per lane at (wave-uniform base) + lane*16B.
__device__ __forceinline__ void async16(const void* g, void* l) {
    __builtin_amdgcn_global_load_lds(
        (const __attribute__((address_space(1))) unsigned*)g,
        (__attribute__((address_space(3))) unsigned*)l, 16, 0, 0);
}

// ---- y := bias broadcast over 64 rows ----
__global__ __launch_bounds__(256)
void init_y_kernel(const float* __restrict__ bias, float* __restrict__ y) {
    const int gid = blockIdx.x * 256 + threadIdx.x;       // 458752 = 64*7168
    const int m  = gid / (Nd / 4);
    const int nq = gid % (Nd / 4);
    ((float4v*)y)[(long)m * (Nd / 4) + nq] = ((const float4v*)bias)[nq];
}

// ---- x f32 -> bf16 into workspace ----
__global__ __launch_bounds__(256)
void cvt_x_kernel(const float* __restrict__ x, unsigned short* __restrict__ o) {
    const int i = (blockIdx.x * 256 + threadIdx.x) * 8;
    float4v a = *(const float4v*)(x + i);
    float4v b = *(const float4v*)(x + i + 4);
    union { unsigned short s[8]; short8 v; } r;
    #pragma unroll
    for (int j = 0; j < 4; ++j) {
        r.s[j]     = (unsigned short)f32_to_bf16_rn(a[j]);
        r.s[4 + j] = (unsigned short)f32_to_bf16_rn(b[j]);
    }
    *(short8*)(o + i) = r.v;
}

// ---- main: grid (448, 4), block 256 ----
__global__ __launch_bounds__(256, 3)
void int4_main_kernel(const unsigned short* __restrict__ xw,
                      const int*            __restrict__ wp,
                      const float*          __restrict__ scales,
                      float*                __restrict__ y)
{
    // 3-stage circular staging + scales. Separate objects for alias analysis.
    __shared__ unsigned wbs[3][2048];   // w half-group: 32 packed rows x 64 n
    __shared__ unsigned xbs[3][2048];   // x half-group: 64 m x 8 k-chunks (bf16x8)
    __shared__ unsigned sb[1024];       // scales: 16 groups x 64 n (f32)

    const int t = threadIdx.x, lane = t & 63, wv = t >> 6;
    const int q = lane >> 4, c = lane & 15;
    const int l4 = lane >> 4, l15 = lane & 15;
    const int n0 = blockIdx.x * 64, kz = blockIdx.y;

    // ---- per-lane DMA source pointers (verified R7, absmax 0.125) ----
    const int* wsrc0; const int* wsrc1;
    {
        int r0 = wv * 8 + 0 * 4 + l4, c0 = (l15 * 4) ^ (((wv * 2 + 0) & 3) << 4);
        int r1 = wv * 8 + 1 * 4 + l4, c1 = (l15 * 4) ^ (((wv * 2 + 1) & 3) << 4);
        wsrc0 = wp + (long)(kz * 1024 + r0) * Nd + n0 + c0;
        wsrc1 = wp + (long)(kz * 1024 + r1) * Nd + n0 + c1;
    }
    const unsigned short* xsrc0; const unsigned short* xsrc1;
    {
        int s0 = wv * 128 + 0 * 64 + lane, m0 = s0 >> 3, k0 = (s0 & 7) ^ (m0 & 7);
        int s1 = wv * 128 + 1 * 64 + lane, m1 = s1 >> 3, k1 = (s1 & 7) ^ (m1 & 7);
        xsrc0 = xw + (long)m0 * Kd + kz * 2048 + k0 * 8;
        xsrc1 = xw + (long)m1 * Kd + kz * 2048 + k1 * 8;
    }
    const int ldof = wv * 512;   // dwords; second instr of a pair adds +256

    auto stage = [&](int hg, unsigned* wbuf, unsigned* xbuf) {
        const long wof = (long)hg * 32 * Nd;    // 32 packed rows per half-group
        const long xof = (long)hg * 64;         // 64 k per half-group
        async16(wsrc0 + wof, wbuf + ldof);
        async16(wsrc1 + wof, wbuf + ldof + 256);
        async16(xsrc0 + xof, xbuf + ldof);
        async16(xsrc1 + xof, xbuf + ldof + 256);
    };

    float4v acc[4] = {};

    auto compute = [&](const unsigned* wbuf, const unsigned* xbuf, int g) {
        const float s   = __builtin_bit_cast(float, sb[g * 64 + wv * 16 + c]);
        const float m8s = -8.0f * s;
        #pragma unroll
        for (int it = 0; it < 2; ++it) {
            union { short8 h; unsigned u[4]; } bu;
            #pragma unroll
            for (int i = 0; i < 4; ++i) {
                unsigned v = wbuf[(it * 16 + q * 4 + i) * 64 + ((wv * 16 + c) ^ (q << 4))];
                float lo = fmaf((float)(v & 15u), s, m8s);          // ==((v&15)-8)*s
                float hi = fmaf((float)((v >> 4) & 15u), s, m8s);
                bu.u[i] = f32_to_bf16_rn(lo) | (f32_to_bf16_rn(hi) << 16);
            }
            #pragma unroll
            for (int mt = 0; mt < 4; ++mt) {
                int m = mt * 16 + c;
                int slot = m * 8 + ((it * 4 + q) ^ (c & 7));        // XOR-swizzled
                short8 a = *(const short8*)(xbuf + slot * 4);
                acc[mt] = __builtin_amdgcn_mfma_f32_16x16x32_bf16(a, bu.h, acc[mt], 0, 0, 0);
            }
        }
    };

    // ---- prologue: scales (one DMA) + stages 0,1 ----
    {
        const float* ssrc = scales + (long)(kz * 16 + (t >> 4)) * Nd + n0 + (t & 15) * 4;
        async16(ssrc, sb + wv * 256);
    }
    stage(0, wbs[0], xbs[0]);
    stage(1, wbs[1], xbs[1]);

    // ---- 32 phases; rotating buffer indices (cur = i%3, nx2 = (i+2)%3) ----
    int cur = 0, nx2 = 2;
    for (int i = 0; i < 31; ++i) {
        // S(i) retired: only S(i+1) (4 DMAs) is newer at this point.
        // Barrier also proves all waves finished compute(i-1) -> buf nx2 reusable.
        asm volatile("s_waitcnt vmcnt(4)\ns_barrier" ::: "memory");
        if (i < 30)
            stage(i + 2, wbs[nx2], xbs[nx2]);
        compute(wbs[cur], xbs[cur], i >> 1);
        cur = (cur == 2) ? 0 : cur + 1;
        nx2 = (nx2 == 2) ? 0 : nx2 + 1;
    }
    asm volatile("s_waitcnt vmcnt(0)\ns_barrier" ::: "memory");
    compute(wbs[cur], xbs[cur], 15);

    // ---- epilogue: C/D row m = mt*16 + q*4 + r, col n = n0 + wv*16 + c ----
    const int nw = n0 + wv * 16 + c;
    #pragma unroll
    for (int mt = 0; mt < 4; ++mt)
        #pragma unroll
        for (int r = 0; r < 4; ++r)
            atomicAdd(&y[(long)(mt * 16 + q * 4 + r) * Nd + nw], acc[mt][r]);
}

// ---- fallback main (no ws): R4 structure, inline f32->bf16 A loads ----
__global__ __launch_bounds__(256, 6)
void int4_main_nows_kernel(const float* __restrict__ xf,
                           const int*   __restrict__ wp,
                           const float* __restrict__ scales,
                           float*       __restrict__ y)
{
    constexpr int LDS_STRIDE = 68;
    __shared__ unsigned lds_w[64 * LDS_STRIDE];
    const int t = threadIdx.x, lane = t & 63, wv = t >> 6;
    const int q = lane >> 4, c = lane & 15;
    const int n0 = blockIdx.x * 64, kz = blockIdx.y;
    const int sr = t >> 4, ss = t & 15;
    const int*   wp_b = wp + (long)(kz * 1024 + sr) * Nd + n0 + 4 * ss;
    const float* sc_b = scales + (long)(kz * 16) * Nd + n0 + 4 * ss;
    const float* xf_b = xf + (long)c * Kd + kz * 2048 + q * 8;
    float4v acc[4] = {};

    for (int g = 0; g < 16; ++g) {
        const float4v s4 = *(const float4v*)(sc_b + (long)g * Nd);
        const int* wg = wp_b + (long)g * 64 * Nd;
        #pragma unroll
        for (int i = 0; i < 4; ++i) {
            int4v v = *(const int4v*)(wg + (long)i * 16 * Nd);
            uint4v pk;
            #pragma unroll
            for (int j = 0; j < 4; ++j) {
                float lo = (float)((v[j] & 15) - 8) * s4[j];
                float hi = (float)(((v[j] >> 4) & 15) - 8) * s4[j];
                pk[j] = f32_to_bf16_rn(lo) | (f32_to_bf16_rn(hi) << 16);
            }
            *(uint4v*)&lds_w[(i * 16 + sr) * LDS_STRIDE + 4 * ss] = pk;
        }
        __syncthreads();
        const float* xg = xf_b + g * 128;
        #pragma unroll
        for (int it = 0; it < 4; ++it) {
            union { short8 h; unsigned u[4]; } bu;
            #pragma unroll
            for (int i = 0; i < 4; ++i)
                bu.u[i] = lds_w[(it * 16 + q * 4 + i) * LDS_STRIDE + wv * 16 + c];
            const short8 b = bu.h;
            const float* xk = xg + it * 32;
            #pragma unroll
            for (int mt = 0; mt < 4; ++mt) {
                float4v a0 = *(const float4v*)(xk + (long)mt * 16 * Kd);
                float4v a1 = *(const float4v*)(xk + (long)mt * 16 * Kd + 4);
                union { unsigned short s[8]; short8 v; } r;
                #pragma unroll
                for (int j = 0; j < 4; ++j) {
                    r.s[j]     = (unsigned short)f32_to_bf16_rn(a0[j]);
                    r.s[4 + j] = (unsigned short)f32_to_bf16_rn(a1[j]);
                }
                acc[mt] = __builtin_amdgcn_mfma_f32_16x16x32_bf16(r.v, b, acc[mt], 0, 0, 0);
            }
        }
        __syncthreads();
    }
    const int nw = n0 + wv * 16 + c;
    #pragma unroll
    for (int mt = 0; mt < 4; ++mt)
        #pragma unroll
        for (int r = 0; r < 4; ++r)
            atomicAdd(&y[(long)(mt * 16 + q * 4 + r) * Nd + nw], acc[mt][r]);
}

extern "C" void kernel_launch(void* const* d_in, const int* in_sizes, int n_in,
                              void* d_out, int out_size, void* d_ws, size_t ws_size,
                              hipStream_t stream) {
    const float* x      = (const float*)d_in[0];
    const int*   wp     = (const int*)d_in[1];
    const float* scales = (const float*)d_in[2];
    const float* bias   = (const float*)d_in[3];
    float*       y      = (float*)d_out;

    init_y_kernel<<<dim3(1792), dim3(256), 0, stream>>>(bias, y);

    const size_t xb_bytes = (size_t)64 * Kd * sizeof(unsigned short); // 1 MB
    dim3 grid(Nd / 64, KSPLIT);   // (448, 4) -> 1792 blocks, 3 resident/CU
    dim3 block(256);

    if (ws_size >= xb_bytes) {
        unsigned short* xb = (unsigned short*)d_ws;
        cvt_x_kernel<<<dim3(256), dim3(256), 0, stream>>>(x, xb);
        int4_main_kernel<<<grid, block, 0, stream>>>(xb, wp, scales, y);
    } else {
        int4_main_nows_kernel<<<grid, block, 0, stream>>>(x, wp, scales, y);
    }
}

// Round 9
// 641.725 us; speedup vs baseline: 1.0471x; 1.0471x over previous
//
#include <hip/hip_runtime.h>

// INT4PackedLinear: y[64,28672] = x[64,8192] @ dequant(w_packed, scales) + bias
// Dtype contract (verified R0-R8): x/scales/bias/y are FLOAT32, w_packed int32.
//
// R8 post-mortem: R7(4 resident blocks)=170us vs R8(3 resident)=211us -- wall
// time ~ serial-sum/residency: inter-block TLP, not intra-block pipelining, is
// what hides latency. R9: maximize residency. Quarter-group phases (32k),
// double-buffered 18KB LDS -> 8 blocks/CU = 32 waves/CU (full occupancy),
// KSPLIT=8, VGPR<=64 via launch_bounds(256,8). vmcnt-safe skeleton kept:
// zero vmem in compute, vmcnt(2) waits, lgkm-only second barrier.

typedef short  short8  __attribute__((ext_vector_type(8)));
typedef float  float4v __attribute__((ext_vector_type(4)));
typedef int    int4v   __attribute__((ext_vector_type(4)));
typedef unsigned int uint4v __attribute__((ext_vector_type(4)));

constexpr int Kd = 8192;
constexpr int Nd = 28672;
constexpr int KSPLIT = 8;           // 8 k-partitions of 1024 k (512 packed rows)
constexpr int PHASES = 32;          // 16 packed rows (32 k) per phase

__device__ __forceinline__ unsigned f32_to_bf16_rn(float f) {
    unsigned u = __builtin_bit_cast(unsigned, f);
    return (u + 0x7FFFu + ((u >> 16) & 1u)) >> 16;
}

// async global->LDS DMA: 16B per lane at (wave-uniform base) + lane*16B.
__device__ __forceinline__ void async16(const void* g, void* l) {
    __builtin_amdgcn_global_load_lds(
        (const __attribute__((address_space(1))) unsigned*)g,
        (__attribute__((address_space(3))) unsigned*)l, 16, 0, 0);
}

// ---- y := bias broadcast over 64 rows ----
__global__ __launch_bounds__(256)
void init_y_kernel(const float* __restrict__ bias, float* __restrict__ y) {
    const int gid = blockIdx.x * 256 + threadIdx.x;       // 458752 = 64*7168
    const int m  = gid / (Nd / 4);
    const int nq = gid % (Nd / 4);
    ((float4v*)y)[(long)m * (Nd / 4) + nq] = ((const float4v*)bias)[nq];
}

// ---- x f32 -> bf16 into workspace ----
__global__ __launch_bounds__(256)
void cvt_x_kernel(const float* __restrict__ x, unsigned short* __restrict__ o) {
    const int i = (blockIdx.x * 256 + threadIdx.x) * 8;
    float4v a = *(const float4v*)(x + i);
    float4v b = *(const float4v*)(x + i + 4);
    union { unsigned short s[8]; short8 v; } r;
    #pragma unroll
    for (int j = 0; j < 4; ++j) {
        r.s[j]     = (unsigned short)f32_to_bf16_rn(a[j]);
        r.s[4 + j] = (unsigned short)f32_to_bf16_rn(b[j]);
    }
    *(short8*)(o + i) = r.v;
}

// ---- main: grid (448, 8), block 256, 8 blocks/CU resident ----
__global__ __launch_bounds__(256, 8)
void int4_main_kernel(const unsigned short* __restrict__ xw,
                      const int*            __restrict__ wp,
                      const float*          __restrict__ scales,
                      float*                __restrict__ y)
{
    // 18 KB total -> 8 blocks/CU (144 KB).
    __shared__ __align__(16) unsigned wb0[1024], wb1[1024]; // 16 rows x 64 n, col-swizzled
    __shared__ __align__(16) unsigned xb0[1024], xb1[1024]; // 256 slots x 16B, slot-swizzled
    __shared__ __align__(16) unsigned sb[512];              // 8 groups x 64 n (f32)

    const int t = threadIdx.x, lane = t & 63, wv = t >> 6;
    const int q = lane >> 4, c = lane & 15;
    const int n0 = blockIdx.x * 64, kz = blockIdx.y;

    // w DMA src (phase p adds p*16*Nd): row = kz*512 + wv*4 + (lane>>4),
    // col swizzled by wave so read addr (q*4+i)*64 + ((wv*16+c)^(q<<4)) is 2-way.
    const int* wsrc = wp + (long)(kz * 512 + wv * 4 + (lane >> 4)) * Nd
                         + n0 + ((4 * (lane & 15)) ^ (wv << 4));
    // x DMA src (phase p adds p*32 bf16): slot s = wv*64+lane -> m = s>>2,
    // stored kq = (s&3)^(m&3); read slot = m*4 + (q^(m&3)).
    const int sx = wv * 64 + lane, mx = sx >> 2, kqx = (sx & 3) ^ (mx & 3);
    const unsigned short* xsrc = xw + (long)mx * Kd + kz * 1024 + kqx * 8;

    // scales: 2 KB staged by waves 0,1 (uniform per-wave predicate, DMA ok)
    if (wv < 2) {
        const int gsl = (wv * 64 + lane) >> 4, csl = 4 * (lane & 15);
        async16(scales + (long)(kz * 8 + gsl) * Nd + n0 + csl, sb + wv * 256);
    }

    auto stage = [&](int p, unsigned* wbuf, unsigned* xbuf) {
        async16(wsrc + (long)p * 16 * Nd, wbuf + wv * 256);
        async16(xsrc + p * 32, xbuf + wv * 256);
    };

    float4v acc[4] = {};

    auto compute = [&](int p, const unsigned* wbuf, const unsigned* xbuf) {
        const float s   = __builtin_bit_cast(float, sb[(p >> 2) * 64 + wv * 16 + c]);
        const float m8s = -8.0f * s;
        union { short8 h; unsigned u[4]; } bu;
        #pragma unroll
        for (int i = 0; i < 4; ++i) {
            unsigned v = wbuf[(q * 4 + i) * 64 + ((wv * 16 + c) ^ (q << 4))];
            float lo = fmaf((float)(v & 15u), s, m8s);           // ==((v&15)-8)*s
            float hi = fmaf((float)((v >> 4) & 15u), s, m8s);
            bu.u[i] = f32_to_bf16_rn(lo) | (f32_to_bf16_rn(hi) << 16);
        }
        #pragma unroll
        for (int mt = 0; mt < 4; ++mt) {
            int m = mt * 16 + c;
            int slot = m * 4 + (q ^ (m & 3));
            short8 a = *(const short8*)(xbuf + slot * 4);
            acc[mt] = __builtin_amdgcn_mfma_f32_16x16x32_bf16(a, bu.h, acc[mt], 0, 0, 0);
        }
    };

    // prologue: phases 0,1 in flight
    stage(0, wb0, xb0);
    stage(1, wb1, xb1);

    // steady state, 2-unrolled (static buffer indices).
    // At each wait: outstanding = S(p) (2 DMAs) + S(p+1) (2) -> vmcnt(2) = S(p) landed.
    for (int p = 0; p < 30; p += 2) {
        asm volatile("s_waitcnt vmcnt(2)\ns_barrier" ::: "memory");
        compute(p, wb0, xb0);
        asm volatile("s_waitcnt lgkmcnt(0)\ns_barrier" ::: "memory");
        stage(p + 2, wb0, xb0);

        asm volatile("s_waitcnt vmcnt(2)\ns_barrier" ::: "memory");
        compute(p + 1, wb1, xb1);
        asm volatile("s_waitcnt lgkmcnt(0)\ns_barrier" ::: "memory");
        stage(p + 3, wb1, xb1);          // p<=28 -> p+3<=31: all phases staged
    }
    asm volatile("s_waitcnt vmcnt(2)\ns_barrier" ::: "memory");
    compute(30, wb0, xb0);
    asm volatile("s_waitcnt vmcnt(0)\ns_barrier" ::: "memory");
    compute(31, wb1, xb1);

    // ---- epilogue: C/D row m = mt*16 + q*4 + r, col n = n0 + wv*16 + c ----
    const int nw = n0 + wv * 16 + c;
    #pragma unroll
    for (int mt = 0; mt < 4; ++mt)
        #pragma unroll
        for (int r = 0; r < 4; ++r)
            atomicAdd(&y[(long)(mt * 16 + q * 4 + r) * Nd + nw], acc[mt][r]);
}

// ---- fallback main (no ws): R4 structure, inline f32->bf16 A loads, grid (448,4) ----
__global__ __launch_bounds__(256, 6)
void int4_main_nows_kernel(const float* __restrict__ xf,
                           const int*   __restrict__ wp,
                           const float* __restrict__ scales,
                           float*       __restrict__ y)
{
    constexpr int LDS_STRIDE = 68;
    __shared__ unsigned lds_w[64 * LDS_STRIDE];
    const int t = threadIdx.x, lane = t & 63, wv = t >> 6;
    const int q = lane >> 4, c = lane & 15;
    const int n0 = blockIdx.x * 64, kz = blockIdx.y;
    const int sr = t >> 4, ss = t & 15;
    const int*   wp_b = wp + (long)(kz * 1024 + sr) * Nd + n0 + 4 * ss;
    const float* sc_b = scales + (long)(kz * 16) * Nd + n0 + 4 * ss;
    const float* xf_b = xf + (long)c * Kd + kz * 2048 + q * 8;
    float4v acc[4] = {};

    for (int g = 0; g < 16; ++g) {
        const float4v s4 = *(const float4v*)(sc_b + (long)g * Nd);
        const int* wg = wp_b + (long)g * 64 * Nd;
        #pragma unroll
        for (int i = 0; i < 4; ++i) {
            int4v v = *(const int4v*)(wg + (long)i * 16 * Nd);
            uint4v pk;
            #pragma unroll
            for (int j = 0; j < 4; ++j) {
                float lo = (float)((v[j] & 15) - 8) * s4[j];
                float hi = (float)(((v[j] >> 4) & 15) - 8) * s4[j];
                pk[j] = f32_to_bf16_rn(lo) | (f32_to_bf16_rn(hi) << 16);
            }
            *(uint4v*)&lds_w[(i * 16 + sr) * LDS_STRIDE + 4 * ss] = pk;
        }
        __syncthreads();
        const float* xg = xf_b + g * 128;
        #pragma unroll
        for (int it = 0; it < 4; ++it) {
            union { short8 h; unsigned u[4]; } bu;
            #pragma unroll
            for (int i = 0; i < 4; ++i)
                bu.u[i] = lds_w[(it * 16 + q * 4 + i) * LDS_STRIDE + wv * 16 + c];
            const short8 b = bu.h;
            const float* xk = xg + it * 32;
            #pragma unroll
            for (int mt = 0; mt < 4; ++mt) {
                float4v a0 = *(const float4v*)(xk + (long)mt * 16 * Kd);
                float4v a1 = *(const float4v*)(xk + (long)mt * 16 * Kd + 4);
                union { unsigned short s[8]; short8 v; } r;
                #pragma unroll
                for (int j = 0; j < 4; ++j) {
                    r.s[j]     = (unsigned short)f32_to_bf16_rn(a0[j]);
                    r.s[4 + j] = (unsigned short)f32_to_bf16_rn(a1[j]);
                }
                acc[mt] = __builtin_amdgcn_mfma_f32_16x16x32_bf16(r.v, b, acc[mt], 0, 0, 0);
            }
        }
        __syncthreads();
    }
    const int nw = n0 + wv * 16 + c;
    #pragma unroll
    for (int mt = 0; mt < 4; ++mt)
        #pragma unroll
        for (int r = 0; r < 4; ++r)
            atomicAdd(&y[(long)(mt * 16 + q * 4 + r) * Nd + nw], acc[mt][r]);
}

extern "C" void kernel_launch(void* const* d_in, const int* in_sizes, int n_in,
                              void* d_out, int out_size, void* d_ws, size_t ws_size,
                              hipStream_t stream) {
    const float* x      = (const float*)d_in[0];
    const int*   wp     = (const int*)d_in[1];
    const float* scales = (const float*)d_in[2];
    const float* bias   = (const float*)d_in[3];
    float*       y      = (float*)d_out;

    init_y_kernel<<<dim3(1792), dim3(256), 0, stream>>>(bias, y);

    const size_t xb_bytes = (size_t)64 * Kd * sizeof(unsigned short); // 1 MB
    dim3 block(256);

    if (ws_size >= xb_bytes) {
        unsigned short* xb = (unsigned short*)d_ws;
        cvt_x_kernel<<<dim3(256), dim3(256), 0, stream>>>(x, xb);
        dim3 grid(Nd / 64, KSPLIT);   // (448, 8) = 3584 blocks, 8 resident/CU
        int4_main_kernel<<<grid, block, 0, stream>>>(xb, wp, scales, y);
    } else {
        dim3 grid(Nd / 64, 4);
        int4_main_nows_kernel<<<grid, block, 0, stream>>>(x, wp, scales, y);
    }
}